// Round 1
// baseline (1165.501 us; speedup 1.0000x reference)
//
#include <hip/hip_runtime.h>
#include <hip/hip_bf16.h>

// Problem constants (fixed by the reference)
#define Bn   4
#define Sn   1024
#define Dn   1024
#define Hn   16
#define dHn  64
#define HB   (Hn * Bn)     // 64
#define MROWS (Bn * Sn)    // 4096

// ---------------------------------------------------------------------------
// Generic fp32 GEMM: C[M,N] = A[M,K] @ B[K,N] (+ resid).  M,N,K % 64 == 0.
// Tile 64x64, BK=16, 256 threads, 4x4 micro-tile per thread.
// ---------------------------------------------------------------------------
__global__ __launch_bounds__(256) void gemm_kernel(
    const float* __restrict__ A, const float* __restrict__ Bm,
    const float* __restrict__ resid, float* __restrict__ C,
    int M, int N, int K) {
  __shared__ float As[16][64];   // [k][m]
  __shared__ float Bs[16][64];   // [k][n]
  const int t  = threadIdx.x;
  const int m0 = blockIdx.y * 64;
  const int n0 = blockIdx.x * 64;
  const int tm = (t / 16) * 4;
  const int tn = (t % 16) * 4;
  const int arow = t / 4;          // 0..63
  const int acol = (t % 4) * 4;    // 0..12
  const int brow = t / 16;         // 0..15
  const int bcol = (t % 16) * 4;   // 0..60
  float acc[4][4] = {};
  for (int k0 = 0; k0 < K; k0 += 16) {
    float4 av = *(const float4*)&A[(size_t)(m0 + arow) * K + k0 + acol];
    As[acol + 0][arow] = av.x;
    As[acol + 1][arow] = av.y;
    As[acol + 2][arow] = av.z;
    As[acol + 3][arow] = av.w;
    *(float4*)&Bs[brow][bcol] =
        *(const float4*)&Bm[(size_t)(k0 + brow) * N + n0 + bcol];
    __syncthreads();
#pragma unroll
    for (int kk = 0; kk < 16; ++kk) {
      float4 a = *(const float4*)&As[kk][tm];
      float4 b = *(const float4*)&Bs[kk][tn];
      float ar[4] = {a.x, a.y, a.z, a.w};
      float br[4] = {b.x, b.y, b.z, b.w};
#pragma unroll
      for (int i = 0; i < 4; ++i)
#pragma unroll
        for (int j = 0; j < 4; ++j) acc[i][j] += ar[i] * br[j];
    }
    __syncthreads();
  }
#pragma unroll
  for (int i = 0; i < 4; ++i) {
    int m = m0 + tm + i;
    float4 r = make_float4(0.f, 0.f, 0.f, 0.f);
    if (resid) r = *(const float4*)&resid[(size_t)m * N + n0 + tn];
    float4 c;
    c.x = acc[i][0] + r.x;
    c.y = acc[i][1] + r.y;
    c.z = acc[i][2] + r.z;
    c.w = acc[i][3] + r.w;
    *(float4*)&C[(size_t)m * N + n0 + tn] = c;
  }
}

// ---------------------------------------------------------------------------
// Scores: attn_raw[hb, q, k] = (Q_hb[q,:] . K_hb[k,:]) / 8, for k-tiles <= q-tile.
// Q,K stored [B,S,D]; head h uses cols h*64..h*64+63.  grid (kt, qt, hb).
// ---------------------------------------------------------------------------
__global__ __launch_bounds__(256) void scores_kernel(
    const float* __restrict__ Q, const float* __restrict__ Kp,
    float* __restrict__ attn) {
  const int kt = blockIdx.x, qt = blockIdx.y, hb = blockIdx.z;
  if (kt > qt) return;  // strictly above diagonal: softmax writes zeros there
  const int h = hb >> 2, b = hb & 3;
  const int q0 = qt * 64, k0 = kt * 64;
  __shared__ float Qs[64][64];  // [c][q]
  __shared__ float Ks[64][64];  // [c][k]
  const int t = threadIdx.x;
  const int r = t / 16, c4 = (t % 16) * 4;
#pragma unroll
  for (int rr = r; rr < 64; rr += 16) {
    float4 qv = *(const float4*)&Q[((size_t)b * Sn + q0 + rr) * Dn + h * dHn + c4];
    Qs[c4 + 0][rr] = qv.x; Qs[c4 + 1][rr] = qv.y;
    Qs[c4 + 2][rr] = qv.z; Qs[c4 + 3][rr] = qv.w;
    float4 kv = *(const float4*)&Kp[((size_t)b * Sn + k0 + rr) * Dn + h * dHn + c4];
    Ks[c4 + 0][rr] = kv.x; Ks[c4 + 1][rr] = kv.y;
    Ks[c4 + 2][rr] = kv.z; Ks[c4 + 3][rr] = kv.w;
  }
  __syncthreads();
  const int tm = (t / 16) * 4, tn = (t % 16) * 4;
  float acc[4][4] = {};
#pragma unroll 8
  for (int kk = 0; kk < 64; ++kk) {
    float4 a = *(const float4*)&Qs[kk][tm];
    float4 b = *(const float4*)&Ks[kk][tn];
    float ar[4] = {a.x, a.y, a.z, a.w};
    float br[4] = {b.x, b.y, b.z, b.w};
#pragma unroll
    for (int i = 0; i < 4; ++i)
#pragma unroll
      for (int j = 0; j < 4; ++j) acc[i][j] += ar[i] * br[j];
  }
#pragma unroll
  for (int i = 0; i < 4; ++i) {
    float4 c;
    c.x = acc[i][0] * 0.125f;
    c.y = acc[i][1] * 0.125f;
    c.z = acc[i][2] * 0.125f;
    c.w = acc[i][3] * 0.125f;
    *(float4*)&attn[((size_t)hb * Sn + q0 + tm + i) * Sn + k0 + tn] = c;
  }
}

// ---------------------------------------------------------------------------
// Causal softmax over one row; writes zeros for k > q.  grid (q=S, hb=HB).
// ---------------------------------------------------------------------------
__global__ __launch_bounds__(256) void softmax_kernel(float* __restrict__ attn) {
  const int q = blockIdx.x, hb = blockIdx.y;
  float* row = attn + ((size_t)hb * Sn + q) * Sn;
  const int t = threadIdx.x;
  float v[4];
  float mx = -1e30f;
#pragma unroll
  for (int i = 0; i < 4; ++i) {
    int k = t + i * 256;
    v[i] = (k <= q) ? row[k] : -1e30f;
    mx = fmaxf(mx, v[i]);
  }
  __shared__ float red[256];
  red[t] = mx;
  __syncthreads();
  for (int s = 128; s > 0; s >>= 1) {
    if (t < s) red[t] = fmaxf(red[t], red[t + s]);
    __syncthreads();
  }
  mx = red[0];
  __syncthreads();
  float sum = 0.f;
#pragma unroll
  for (int i = 0; i < 4; ++i) {
    v[i] = __expf(v[i] - mx);  // invalid lanes: exp(-huge) == 0
    sum += v[i];
  }
  red[t] = sum;
  __syncthreads();
  for (int s = 128; s > 0; s >>= 1) {
    if (t < s) red[t] += red[t + s];
    __syncthreads();
  }
  const float inv = 1.0f / red[0];
#pragma unroll
  for (int i = 0; i < 4; ++i) row[t + i * 256] = v[i] * inv;
}

// ---------------------------------------------------------------------------
// concat[b, s, h*64+j] = sum_k attn[hb, s, k] * V[b, k, h*64+j]
// grid (stile=16, hb=64); k-tiles 0..stile (upper zeros already exact).
// ---------------------------------------------------------------------------
__global__ __launch_bounds__(256) void av_kernel(
    const float* __restrict__ attn, const float* __restrict__ V,
    float* __restrict__ concat) {
  const int st = blockIdx.x, hb = blockIdx.y;
  const int h = hb >> 2, b = hb & 3;
  const int s0 = st * 64;
  __shared__ float As[64][64];  // [k][s]
  __shared__ float Vs[64][64];  // [k][j]
  const int t = threadIdx.x;
  const int r = t / 16, c4 = (t % 16) * 4;
  const int tm = (t / 16) * 4, tn = (t % 16) * 4;
  float acc[4][4] = {};
  for (int kt = 0; kt <= st; ++kt) {
    const int k0 = kt * 64;
#pragma unroll
    for (int rr = r; rr < 64; rr += 16) {
      float4 av = *(const float4*)&attn[((size_t)hb * Sn + s0 + rr) * Sn + k0 + c4];
      As[c4 + 0][rr] = av.x; As[c4 + 1][rr] = av.y;
      As[c4 + 2][rr] = av.z; As[c4 + 3][rr] = av.w;
      *(float4*)&Vs[rr][c4] =
          *(const float4*)&V[((size_t)b * Sn + k0 + rr) * Dn + h * dHn + c4];
    }
    __syncthreads();
#pragma unroll 8
    for (int kk = 0; kk < 64; ++kk) {
      float4 a = *(const float4*)&As[kk][tm];
      float4 bv = *(const float4*)&Vs[kk][tn];
      float ar[4] = {a.x, a.y, a.z, a.w};
      float br[4] = {bv.x, bv.y, bv.z, bv.w};
#pragma unroll
      for (int i = 0; i < 4; ++i)
#pragma unroll
        for (int j = 0; j < 4; ++j) acc[i][j] += ar[i] * br[j];
    }
    __syncthreads();
  }
#pragma unroll
  for (int i = 0; i < 4; ++i) {
    float4 c = make_float4(acc[i][0], acc[i][1], acc[i][2], acc[i][3]);
    *(float4*)&concat[((size_t)b * Sn + s0 + tm + i) * Dn + h * dHn + tn] = c;
  }
}

// ---------------------------------------------------------------------------
// In-place row LayerNorm on out[B*S, D].  grid (B*S), 256 threads.
// ---------------------------------------------------------------------------
__global__ __launch_bounds__(256) void ln_kernel(
    float* __restrict__ out, const float* __restrict__ gamma,
    const float* __restrict__ beta) {
  const int row = blockIdx.x;
  float* p = out + (size_t)row * Dn;
  const int t = threadIdx.x;
  float v[4];
  float s = 0.f, s2 = 0.f;
#pragma unroll
  for (int i = 0; i < 4; ++i) {
    v[i] = p[t + i * 256];
    s += v[i];
    s2 += v[i] * v[i];
  }
  __shared__ float r1[256], r2[256];
  r1[t] = s; r2[t] = s2;
  __syncthreads();
  for (int st = 128; st > 0; st >>= 1) {
    if (t < st) { r1[t] += r1[t + st]; r2[t] += r2[t + st]; }
    __syncthreads();
  }
  const float mu  = r1[0] * (1.0f / Dn);
  const float var = r2[0] * (1.0f / Dn) - mu * mu;
  const float rstd = rsqrtf(var + 1e-5f);
#pragma unroll
  for (int i = 0; i < 4; ++i) {
    int c = t + i * 256;
    p[c] = (v[i] - mu) * rstd * gamma[c] + beta[c];
  }
}

// ---------------------------------------------------------------------------
extern "C" void kernel_launch(void* const* d_in, const int* in_sizes, int n_in,
                              void* d_out, int out_size, void* d_ws, size_t ws_size,
                              hipStream_t stream) {
  const float* q_in  = (const float*)d_in[0];
  const float* k_in  = (const float*)d_in[1];
  const float* v_in  = (const float*)d_in[2];
  const float* Wq    = (const float*)d_in[3];
  const float* Wk    = (const float*)d_in[4];
  const float* Wv    = (const float*)d_in[5];
  const float* Wo    = (const float*)d_in[6];
  const float* gamma = (const float*)d_in[7];
  const float* beta  = (const float*)d_in[8];

  float* out  = (float*)d_out;                         // [B,S,D]
  float* attn = out + (size_t)Bn * Sn * Dn;            // [H,B,S,S]

  const size_t QN = (size_t)Bn * Sn * Dn;              // 4M elements
  float* ws = (float*)d_ws;
  float* Qp = ws;
  float* Kp = ws + QN;
  float* Vp = ws + 2 * QN;
  float* Cc = ws + 3 * QN;                             // concat

  dim3 gg(Dn / 64, MROWS / 64);                        // (16, 64)
  gemm_kernel<<<gg, 256, 0, stream>>>(q_in, Wq, nullptr, Qp, MROWS, Dn, Dn);
  gemm_kernel<<<gg, 256, 0, stream>>>(k_in, Wk, nullptr, Kp, MROWS, Dn, Dn);
  gemm_kernel<<<gg, 256, 0, stream>>>(v_in, Wv, nullptr, Vp, MROWS, Dn, Dn);

  scores_kernel<<<dim3(Sn / 64, Sn / 64, HB), 256, 0, stream>>>(Qp, Kp, attn);
  softmax_kernel<<<dim3(Sn, HB), 256, 0, stream>>>(attn);
  av_kernel<<<dim3(Sn / 64, HB), 256, 0, stream>>>(attn, Vp, Cc);

  gemm_kernel<<<gg, 256, 0, stream>>>(Cc, Wo, q_in, out, MROWS, Dn, Dn);
  ln_kernel<<<MROWS, 256, 0, stream>>>(out, gamma, beta);
}

// Round 2
// 626.167 us; speedup vs baseline: 1.8613x; 1.8613x over previous
//
#include <hip/hip_runtime.h>
#include <hip/hip_bf16.h>

// Problem constants (fixed by the reference)
#define Bn   4
#define Sn   1024
#define Dn   1024
#define Hn   16
#define dHn  64
#define HB   (Hn * Bn)     // 64
#define MROWS (Bn * Sn)    // 4096

typedef __attribute__((ext_vector_type(8))) short bf16x8;
typedef __attribute__((ext_vector_type(4))) float f32x4;

__device__ __forceinline__ ushort f2bf(float x) {
  union { float f; unsigned u; } v; v.f = x;
  unsigned r = v.u + 0x7FFF + ((v.u >> 16) & 1);   // round-to-nearest-even
  return (ushort)(r >> 16);
}

// ---------------------------------------------------------------------------
// fp32 -> bf16 flat cast.  n must be multiple of 1024.  grid: n/1024 blocks.
// ---------------------------------------------------------------------------
__global__ __launch_bounds__(256) void cast_kernel(
    const float* __restrict__ in, ushort* __restrict__ out) {
  int idx = blockIdx.x * 256 + threadIdx.x;   // float4 index
  float4 v = *(const float4*)&in[(size_t)idx * 4];
  ushort4 o;
  o.x = f2bf(v.x); o.y = f2bf(v.y); o.z = f2bf(v.z); o.w = f2bf(v.w);
  *(ushort4*)&out[(size_t)idx * 4] = o;
}

// ---------------------------------------------------------------------------
// W [K,N] fp32 -> WT [N,K] bf16.  Tile 64x64.  grid (N/64, K/64).
// ---------------------------------------------------------------------------
__global__ __launch_bounds__(256) void transpose_cast_kernel(
    const float* __restrict__ W, ushort* __restrict__ WT, int K, int N) {
  __shared__ ushort T[64 * 72];   // [n][k], stride 72
  const int k0 = blockIdx.y * 64, n0 = blockIdx.x * 64;
  const int t = threadIdx.x;
  const int r = t >> 4, c4 = (t & 15) * 4;
#pragma unroll
  for (int i = 0; i < 4; ++i) {
    int row = r + i * 16;   // k within tile
    float4 v = *(const float4*)&W[(size_t)(k0 + row) * N + n0 + c4];
    T[(c4 + 0) * 72 + row] = f2bf(v.x);
    T[(c4 + 1) * 72 + row] = f2bf(v.y);
    T[(c4 + 2) * 72 + row] = f2bf(v.z);
    T[(c4 + 3) * 72 + row] = f2bf(v.w);
  }
  __syncthreads();
#pragma unroll
  for (int i = 0; i < 2; ++i) {
    int c = t + i * 256;
    int n = c >> 3, kg = (c & 7) * 8;
    *(ulonglong2*)&WT[(size_t)(n0 + n) * K + k0 + kg] =
        *(const ulonglong2*)&T[n * 72 + kg];
  }
}

// ---------------------------------------------------------------------------
// bf16 MFMA GEMM (BT form): C[M,N] = A[M,K] @ Bt[N,K]^T.
// Tile 128x128, BK=32, 256 threads = 4 waves (2x2 of 64x64).
// MODE 0: fp32 out (+ optional resid)
// MODE 1: bf16 row-major out (LDS-transposed coalesced store)
// MODE 2: bf16 batch-transposed out: C[(b*N + n)*Sn + s], b=m/Sn, s=m%Sn
// ---------------------------------------------------------------------------
template <int MODE>
__global__ __launch_bounds__(256) void gemm_bt(
    const ushort* __restrict__ A, const ushort* __restrict__ Bt,
    const float* __restrict__ resid, void* __restrict__ Cout,
    int M, int N, int K) {
  __shared__ ushort lds[17408];               // 34 KB (staging 20KB; MODE1 Cs 34KB)
  ushort* As = lds;                           // 128 x 40
  ushort* Bs = lds + 5120;                    // 128 x 40
  const int t = threadIdx.x;
  const int wid = t >> 6, lane = t & 63;
  const int wr = (wid >> 1) * 64, wc = (wid & 1) * 64;
  const int l16 = lane & 15, quad = lane >> 4;
  const int m0 = blockIdx.y * 128, n0 = blockIdx.x * 128;
  f32x4 acc[4][4] = {};
  for (int k0 = 0; k0 < K; k0 += 32) {
#pragma unroll
    for (int i = 0; i < 2; ++i) {
      int c = t + i * 256;
      int row = c >> 2, cg = (c & 3) * 8;
      *(ulonglong2*)&As[row * 40 + cg] =
          *(const ulonglong2*)&A[(size_t)(m0 + row) * K + k0 + cg];
      *(ulonglong2*)&Bs[row * 40 + cg] =
          *(const ulonglong2*)&Bt[(size_t)(n0 + row) * K + k0 + cg];
    }
    __syncthreads();
    bf16x8 af[4], bfr[4];
#pragma unroll
    for (int mi = 0; mi < 4; ++mi)
      af[mi] = *(const bf16x8*)&As[(wr + mi * 16 + l16) * 40 + quad * 8];
#pragma unroll
    for (int ni = 0; ni < 4; ++ni)
      bfr[ni] = *(const bf16x8*)&Bs[(wc + ni * 16 + l16) * 40 + quad * 8];
#pragma unroll
    for (int mi = 0; mi < 4; ++mi)
#pragma unroll
      for (int ni = 0; ni < 4; ++ni)
        acc[mi][ni] = __builtin_amdgcn_mfma_f32_16x16x32_bf16(
            af[mi], bfr[ni], acc[mi][ni], 0, 0, 0);
    __syncthreads();
  }
  if (MODE == 0) {
    float* C = (float*)Cout;
#pragma unroll
    for (int mi = 0; mi < 4; ++mi)
#pragma unroll
      for (int ni = 0; ni < 4; ++ni) {
        int n = n0 + wc + ni * 16 + l16;
#pragma unroll
        for (int r = 0; r < 4; ++r) {
          int m = m0 + wr + mi * 16 + quad * 4 + r;
          float v = acc[mi][ni][r];
          if (resid) v += resid[(size_t)m * N + n];
          C[(size_t)m * N + n] = v;
        }
      }
  } else if (MODE == 2) {
    ushort* C = (ushort*)Cout;
#pragma unroll
    for (int mi = 0; mi < 4; ++mi) {
      int mb = m0 + wr + mi * 16 + quad * 4;
      int b = mb >> 10, s = mb & 1023;
#pragma unroll
      for (int ni = 0; ni < 4; ++ni) {
        int n = n0 + wc + ni * 16 + l16;
        ushort4 o;
        o.x = f2bf(acc[mi][ni][0]);
        o.y = f2bf(acc[mi][ni][1]);
        o.z = f2bf(acc[mi][ni][2]);
        o.w = f2bf(acc[mi][ni][3]);
        *(ushort4*)&C[((size_t)b * N + n) * Sn + s] = o;
      }
    }
  } else {  // MODE 1: stage through LDS for coalesced bf16 row-major store
    ushort* Cs = lds;   // 128 x 136
#pragma unroll
    for (int mi = 0; mi < 4; ++mi)
#pragma unroll
      for (int ni = 0; ni < 4; ++ni) {
        int col = wc + ni * 16 + l16;
#pragma unroll
        for (int r = 0; r < 4; ++r)
          Cs[(wr + mi * 16 + quad * 4 + r) * 136 + col] = f2bf(acc[mi][ni][r]);
      }
    __syncthreads();
    ushort* C = (ushort*)Cout;
#pragma unroll
    for (int i = 0; i < 8; ++i) {
      int c = t + i * 256;
      int row = c >> 4, cg = (c & 15) * 8;
      *(ulonglong2*)&C[(size_t)(m0 + row) * N + n0 + cg] =
          *(const ulonglong2*)&Cs[row * 136 + cg];
    }
  }
}

// ---------------------------------------------------------------------------
// Scores via MFMA: attn[hb,q,k] = (Q_hb[q,:].K_hb[k,:])/8 for 128x128 tiles
// with kt <= qt.  Q,K are bf16 [B,S,D], head h = cols h*64..h*64+63.
// grid (kt=8, qt=8, hb=64), 256 threads.
// ---------------------------------------------------------------------------
__global__ __launch_bounds__(256) void scores_mfma(
    const ushort* __restrict__ Q, const ushort* __restrict__ Kb,
    float* __restrict__ attn) {
  const int kt = blockIdx.x, qt = blockIdx.y, hb = blockIdx.z;
  if (kt > qt) return;
  const int h = hb >> 2, b = hb & 3;
  const int q0 = qt * 128, k0 = kt * 128;
  __shared__ ushort lds[18432];
  ushort* Qs = lds;          // 128 x 72
  ushort* Ks = lds + 9216;   // 128 x 72
  const int t = threadIdx.x;
  const int wid = t >> 6, lane = t & 63;
  const int wr = (wid >> 1) * 64, wc = (wid & 1) * 64;
  const int l16 = lane & 15, quad = lane >> 4;
#pragma unroll
  for (int i = 0; i < 4; ++i) {
    int c = t + i * 256;
    int row = c >> 3, cg = (c & 7) * 8;
    *(ulonglong2*)&Qs[row * 72 + cg] =
        *(const ulonglong2*)&Q[((size_t)b * Sn + q0 + row) * Dn + h * dHn + cg];
    *(ulonglong2*)&Ks[row * 72 + cg] =
        *(const ulonglong2*)&Kb[((size_t)b * Sn + k0 + row) * Dn + h * dHn + cg];
  }
  __syncthreads();
  f32x4 acc[4][4] = {};
#pragma unroll
  for (int ks = 0; ks < 2; ++ks) {
    bf16x8 af[4], bfr[4];
#pragma unroll
    for (int mi = 0; mi < 4; ++mi)
      af[mi] = *(const bf16x8*)&Qs[(wr + mi * 16 + l16) * 72 + ks * 32 + quad * 8];
#pragma unroll
    for (int ni = 0; ni < 4; ++ni)
      bfr[ni] = *(const bf16x8*)&Ks[(wc + ni * 16 + l16) * 72 + ks * 32 + quad * 8];
#pragma unroll
    for (int mi = 0; mi < 4; ++mi)
#pragma unroll
      for (int ni = 0; ni < 4; ++ni)
        acc[mi][ni] = __builtin_amdgcn_mfma_f32_16x16x32_bf16(
            af[mi], bfr[ni], acc[mi][ni], 0, 0, 0);
  }
#pragma unroll
  for (int mi = 0; mi < 4; ++mi)
#pragma unroll
    for (int ni = 0; ni < 4; ++ni) {
      int k = k0 + wc + ni * 16 + l16;
#pragma unroll
      for (int r = 0; r < 4; ++r) {
        int q = q0 + wr + mi * 16 + quad * 4 + r;
        attn[((size_t)hb * Sn + q) * Sn + k] = acc[mi][ni][r] * 0.125f;
      }
    }
}

// ---------------------------------------------------------------------------
// Causal softmax over one row; writes zeros for k > q.  grid (q=S, hb=HB).
// ---------------------------------------------------------------------------
__global__ __launch_bounds__(256) void softmax_kernel(float* __restrict__ attn) {
  const int q = blockIdx.x, hb = blockIdx.y;
  float* row = attn + ((size_t)hb * Sn + q) * Sn;
  const int t = threadIdx.x;
  float v[4];
  float mx = -1e30f;
#pragma unroll
  for (int i = 0; i < 4; ++i) {
    int k = t + i * 256;
    v[i] = (k <= q) ? row[k] : -1e30f;
    mx = fmaxf(mx, v[i]);
  }
  __shared__ float red[256];
  red[t] = mx;
  __syncthreads();
  for (int s = 128; s > 0; s >>= 1) {
    if (t < s) red[t] = fmaxf(red[t], red[t + s]);
    __syncthreads();
  }
  mx = red[0];
  __syncthreads();
  float sum = 0.f;
#pragma unroll
  for (int i = 0; i < 4; ++i) {
    v[i] = __expf(v[i] - mx);
    sum += v[i];
  }
  red[t] = sum;
  __syncthreads();
  for (int s = 128; s > 0; s >>= 1) {
    if (t < s) red[t] += red[t + s];
    __syncthreads();
  }
  const float inv = 1.0f / red[0];
#pragma unroll
  for (int i = 0; i < 4; ++i) row[t + i * 256] = v[i] * inv;
}

// ---------------------------------------------------------------------------
// AV via MFMA: concat[b,s,h*64+j] = sum_k attn[hb,s,k] * V[b,k,h*64+j].
// attn fp32 (cast to bf16 while staging); Vt bf16 [b][n][s] (n = h*64+j).
// Block: 128 s-rows x 64 j-cols, 4 waves of 32 rows.  grid (S/128=8, hb=64).
// Output concat bf16 [B*S, D].
// ---------------------------------------------------------------------------
__global__ __launch_bounds__(256) void av_mfma(
    const float* __restrict__ attn, const ushort* __restrict__ Vt,
    ushort* __restrict__ Cc) {
  const int st = blockIdx.x, hb = blockIdx.y;
  const int h = hb >> 2, b = hb & 3;
  const int s0 = st * 128;
  __shared__ ushort lds[13824];
  ushort* As = lds;          // 128 x 72 (s x k)
  ushort* Bs = lds + 9216;   // 64 x 72  (j x k)
  const int t = threadIdx.x;
  const int wid = t >> 6, lane = t & 63;
  const int l16 = lane & 15, quad = lane >> 4;
  f32x4 acc[2][4] = {};
  const int nkt = st * 2 + 2;   // k-tiles of 64 covering k < s0+128
  for (int kt = 0; kt < nkt; ++kt) {
    const int k0 = kt * 64;
#pragma unroll
    for (int i = 0; i < 8; ++i) {
      int c = t + i * 256;
      int row = c >> 4, cg = (c & 15) * 4;
      float4 v = *(const float4*)&attn[((size_t)hb * Sn + s0 + row) * Sn + k0 + cg];
      ushort4 o;
      o.x = f2bf(v.x); o.y = f2bf(v.y); o.z = f2bf(v.z); o.w = f2bf(v.w);
      *(ushort4*)&As[row * 72 + cg] = o;
    }
#pragma unroll
    for (int i = 0; i < 2; ++i) {
      int c = t + i * 256;
      int row = c >> 3, cg = (c & 7) * 8;
      *(ulonglong2*)&Bs[row * 72 + cg] =
          *(const ulonglong2*)&Vt[((size_t)b * Dn + h * dHn + row) * Sn + k0 + cg];
    }
    __syncthreads();
#pragma unroll
    for (int ks = 0; ks < 2; ++ks) {
      bf16x8 af[2], bfr[4];
#pragma unroll
      for (int mi = 0; mi < 2; ++mi)
        af[mi] = *(const bf16x8*)&As[(wid * 32 + mi * 16 + l16) * 72 + ks * 32 + quad * 8];
#pragma unroll
      for (int ni = 0; ni < 4; ++ni)
        bfr[ni] = *(const bf16x8*)&Bs[(ni * 16 + l16) * 72 + ks * 32 + quad * 8];
#pragma unroll
      for (int mi = 0; mi < 2; ++mi)
#pragma unroll
        for (int ni = 0; ni < 4; ++ni)
          acc[mi][ni] = __builtin_amdgcn_mfma_f32_16x16x32_bf16(
              af[mi], bfr[ni], acc[mi][ni], 0, 0, 0);
    }
    __syncthreads();
  }
#pragma unroll
  for (int mi = 0; mi < 2; ++mi)
#pragma unroll
    for (int ni = 0; ni < 4; ++ni) {
      int n = h * dHn + ni * 16 + l16;
#pragma unroll
      for (int r = 0; r < 4; ++r) {
        int s = s0 + wid * 32 + mi * 16 + quad * 4 + r;
        Cc[((size_t)b * Sn + s) * Dn + n] = f2bf(acc[mi][ni][r]);
      }
    }
}

// ---------------------------------------------------------------------------
// In-place row LayerNorm on out[B*S, D].  grid (B*S), 256 threads.
// ---------------------------------------------------------------------------
__global__ __launch_bounds__(256) void ln_kernel(
    float* __restrict__ out, const float* __restrict__ gamma,
    const float* __restrict__ beta) {
  const int row = blockIdx.x;
  float* p = out + (size_t)row * Dn;
  const int t = threadIdx.x;
  float v[4];
  float s = 0.f, s2 = 0.f;
#pragma unroll
  for (int i = 0; i < 4; ++i) {
    v[i] = p[t + i * 256];
    s += v[i];
    s2 += v[i] * v[i];
  }
  __shared__ float r1[256], r2[256];
  r1[t] = s; r2[t] = s2;
  __syncthreads();
  for (int st = 128; st > 0; st >>= 1) {
    if (t < st) { r1[t] += r1[t + st]; r2[t] += r2[t + st]; }
    __syncthreads();
  }
  const float mu  = r1[0] * (1.0f / Dn);
  const float var = r2[0] * (1.0f / Dn) - mu * mu;
  const float rstd = rsqrtf(var + 1e-5f);
#pragma unroll
  for (int i = 0; i < 4; ++i) {
    int c = t + i * 256;
    p[c] = (v[i] - mu) * rstd * gamma[c] + beta[c];
  }
}

// ---------------------------------------------------------------------------
extern "C" void kernel_launch(void* const* d_in, const int* in_sizes, int n_in,
                              void* d_out, int out_size, void* d_ws, size_t ws_size,
                              hipStream_t stream) {
  const float* q_in  = (const float*)d_in[0];
  const float* k_in  = (const float*)d_in[1];
  const float* v_in  = (const float*)d_in[2];
  const float* Wq    = (const float*)d_in[3];
  const float* Wk    = (const float*)d_in[4];
  const float* Wv    = (const float*)d_in[5];
  const float* Wo    = (const float*)d_in[6];
  const float* gamma = (const float*)d_in[7];
  const float* beta  = (const float*)d_in[8];

  float* out  = (float*)d_out;                // [B,S,D]
  float* attn = out + (size_t)Bn * Sn * Dn;   // [H,B,S,S]

  const size_t QN = (size_t)Bn * Sn * Dn;     // 4M elements
  ushort* ws  = (ushort*)d_ws;
  ushort* qbf = ws;                           // [B*S, D] bf16
  ushort* kbf = qbf + QN;
  ushort* vbf = kbf + QN;
  ushort* WqT = vbf + QN;                     // [N,K] bf16, 1M each
  ushort* WkT = WqT + (size_t)Dn * Dn;
  ushort* WvT = WkT + (size_t)Dn * Dn;
  ushort* WoT = WvT + (size_t)Dn * Dn;
  ushort* Qp  = WoT + (size_t)Dn * Dn;        // [B*S, D] bf16
  ushort* Kp  = Qp + QN;
  ushort* Vt  = Kp + QN;                      // [B][D][S] bf16
  ushort* Cc  = Vt + QN;                      // [B*S, D] bf16

  cast_kernel<<<QN / 1024, 256, 0, stream>>>(q_in, qbf);
  cast_kernel<<<QN / 1024, 256, 0, stream>>>(k_in, kbf);
  cast_kernel<<<QN / 1024, 256, 0, stream>>>(v_in, vbf);

  dim3 tg(Dn / 64, Dn / 64);
  transpose_cast_kernel<<<tg, 256, 0, stream>>>(Wq, WqT, Dn, Dn);
  transpose_cast_kernel<<<tg, 256, 0, stream>>>(Wk, WkT, Dn, Dn);
  transpose_cast_kernel<<<tg, 256, 0, stream>>>(Wv, WvT, Dn, Dn);
  transpose_cast_kernel<<<tg, 256, 0, stream>>>(Wo, WoT, Dn, Dn);

  dim3 gg(Dn / 128, MROWS / 128);             // (8, 32)
  gemm_bt<1><<<gg, 256, 0, stream>>>(qbf, WqT, nullptr, Qp, MROWS, Dn, Dn);
  gemm_bt<1><<<gg, 256, 0, stream>>>(kbf, WkT, nullptr, Kp, MROWS, Dn, Dn);
  gemm_bt<2><<<gg, 256, 0, stream>>>(vbf, WvT, nullptr, Vt, MROWS, Dn, Dn);

  scores_mfma<<<dim3(Sn / 128, Sn / 128, HB), 256, 0, stream>>>(Qp, Kp, attn);
  softmax_kernel<<<dim3(Sn, HB), 256, 0, stream>>>(attn);
  av_mfma<<<dim3(Sn / 128, HB), 256, 0, stream>>>(attn, Vt, Cc);

  gemm_bt<0><<<gg, 256, 0, stream>>>(Cc, WoT, q_in, out, MROWS, Dn, Dn);
  ln_kernel<<<MROWS, 256, 0, stream>>>(out, gamma, beta);
}

// Round 3
// 539.665 us; speedup vs baseline: 2.1597x; 1.1603x over previous
//
#include <hip/hip_runtime.h>
#include <hip/hip_bf16.h>

// Problem constants (fixed by the reference)
#define Bn   4
#define Sn   1024
#define Dn   1024
#define Hn   16
#define dHn  64
#define HB   (Hn * Bn)     // 64
#define MROWS (Bn * Sn)    // 4096

typedef __attribute__((ext_vector_type(8))) short bf16x8;
typedef __attribute__((ext_vector_type(4))) float f32x4;

__device__ __forceinline__ ushort f2bf(float x) {
  union { float f; unsigned u; } v; v.f = x;
  unsigned r = v.u + 0x7FFF + ((v.u >> 16) & 1);   // round-to-nearest-even
  return (ushort)(r >> 16);
}
__device__ __forceinline__ float bf2f(ushort u) {
  union { unsigned u; float f; } v; v.u = ((unsigned)u) << 16; return v.f;
}

// async global->LDS, 16B per lane; lds dest = wave-uniform base + lane*16
__device__ __forceinline__ void load_lds16(const void* g, void* l) {
  __builtin_amdgcn_global_load_lds(
      (const __attribute__((address_space(1))) unsigned int*)g,
      (__attribute__((address_space(3))) unsigned int*)l, 16, 0, 0);
}

// ---------------------------------------------------------------------------
// fp32 -> bf16 flat cast.  n must be multiple of 1024.  grid: n/1024 blocks.
// ---------------------------------------------------------------------------
__global__ __launch_bounds__(256) void cast_kernel(
    const float* __restrict__ in, ushort* __restrict__ out) {
  int idx = blockIdx.x * 256 + threadIdx.x;   // float4 index
  float4 v = *(const float4*)&in[(size_t)idx * 4];
  ushort4 o;
  o.x = f2bf(v.x); o.y = f2bf(v.y); o.z = f2bf(v.z); o.w = f2bf(v.w);
  *(ushort4*)&out[(size_t)idx * 4] = o;
}

// ---------------------------------------------------------------------------
// W [K,N] fp32 -> WT [N,K] bf16.  Tile 64x64.  grid (N/64, K/64).
// ---------------------------------------------------------------------------
__global__ __launch_bounds__(256) void transpose_cast_kernel(
    const float* __restrict__ W, ushort* __restrict__ WT, int K, int N) {
  __shared__ ushort T[64 * 72];   // [n][k], stride 72
  const int k0 = blockIdx.y * 64, n0 = blockIdx.x * 64;
  const int t = threadIdx.x;
  const int r = t >> 4, c4 = (t & 15) * 4;
#pragma unroll
  for (int i = 0; i < 4; ++i) {
    int row = r + i * 16;   // k within tile
    float4 v = *(const float4*)&W[(size_t)(k0 + row) * N + n0 + c4];
    T[(c4 + 0) * 72 + row] = f2bf(v.x);
    T[(c4 + 1) * 72 + row] = f2bf(v.y);
    T[(c4 + 2) * 72 + row] = f2bf(v.z);
    T[(c4 + 3) * 72 + row] = f2bf(v.w);
  }
  __syncthreads();
#pragma unroll
  for (int i = 0; i < 2; ++i) {
    int c = t + i * 256;
    int n = c >> 3, kg = (c & 7) * 8;
    *(ulonglong2*)&WT[(size_t)(n0 + n) * K + k0 + kg] =
        *(const ulonglong2*)&T[n * 72 + kg];
  }
}

// ---------------------------------------------------------------------------
// bf16 MFMA GEMM (BT form): C[M,N] = A[M,K] @ Bt[N,K]^T.
// Tile 128x128, BK=32, 256 threads = 4 waves (2x2 of 64x64).
// m97 staging: global_load_lds width=16 into unpadded 128x32 tiles.
// MODE 0: fp32 out (+ optional resid)
// MODE 1: bf16 row-major out (LDS-transposed coalesced store)
// MODE 2: bf16 batch-transposed out: C[(b*N + n)*Sn + s], b=m/Sn, s=m%Sn
// ---------------------------------------------------------------------------
template <int MODE>
__global__ __launch_bounds__(256) void gemm_bt(
    const ushort* __restrict__ A, const ushort* __restrict__ Bt,
    const float* __restrict__ resid, void* __restrict__ Cout,
    int M, int N, int K) {
  __shared__ ushort lds[MODE == 1 ? 17408 : 8192];  // staging 16KB; MODE1 Cs 34KB
  ushort* As = lds;          // 128 x 32 (unpadded, k-contig)
  ushort* Bs = lds + 4096;   // 128 x 32
  const int t = threadIdx.x;
  const int w = t >> 6, lane = t & 63;
  const int wr = (w >> 1) * 64, wc = (w & 1) * 64;
  const int l16 = lane & 15, quad = lane >> 4;
  const int m0 = blockIdx.y * 128, n0 = blockIdx.x * 128;
  const int srow = (lane >> 2);          // 0..15 within 16-row chunk
  const int scol = (lane & 3) * 8;       // k-offset in ushorts
  f32x4 acc[4][4] = {};
  for (int k0 = 0; k0 < K; k0 += 32) {
#pragma unroll
    for (int c = 0; c < 2; ++c) {
      int row = w * 32 + c * 16 + srow;
      load_lds16(&A[(size_t)(m0 + row) * K + k0 + scol],
                 &As[(size_t)w * 1024 + c * 512]);
      load_lds16(&Bt[(size_t)(n0 + row) * K + k0 + scol],
                 &Bs[(size_t)w * 1024 + c * 512]);
    }
    __syncthreads();
    bf16x8 af[4], bfr[4];
#pragma unroll
    for (int mi = 0; mi < 4; ++mi)
      af[mi] = *(const bf16x8*)&As[(wr + mi * 16 + l16) * 32 + quad * 8];
#pragma unroll
    for (int ni = 0; ni < 4; ++ni)
      bfr[ni] = *(const bf16x8*)&Bs[(wc + ni * 16 + l16) * 32 + quad * 8];
#pragma unroll
    for (int mi = 0; mi < 4; ++mi)
#pragma unroll
      for (int ni = 0; ni < 4; ++ni)
        acc[mi][ni] = __builtin_amdgcn_mfma_f32_16x16x32_bf16(
            af[mi], bfr[ni], acc[mi][ni], 0, 0, 0);
    __syncthreads();
  }
  if (MODE == 0) {
    float* C = (float*)Cout;
#pragma unroll
    for (int mi = 0; mi < 4; ++mi)
#pragma unroll
      for (int ni = 0; ni < 4; ++ni) {
        int n = n0 + wc + ni * 16 + l16;
#pragma unroll
        for (int r = 0; r < 4; ++r) {
          int m = m0 + wr + mi * 16 + quad * 4 + r;
          float v = acc[mi][ni][r];
          if (resid) v += resid[(size_t)m * N + n];
          C[(size_t)m * N + n] = v;
        }
      }
  } else if (MODE == 2) {
    ushort* C = (ushort*)Cout;
#pragma unroll
    for (int mi = 0; mi < 4; ++mi) {
      int mb = m0 + wr + mi * 16 + quad * 4;
      int b = mb >> 10, s = mb & 1023;
#pragma unroll
      for (int ni = 0; ni < 4; ++ni) {
        int n = n0 + wc + ni * 16 + l16;
        ushort4 o;
        o.x = f2bf(acc[mi][ni][0]);
        o.y = f2bf(acc[mi][ni][1]);
        o.z = f2bf(acc[mi][ni][2]);
        o.w = f2bf(acc[mi][ni][3]);
        *(ushort4*)&C[((size_t)b * N + n) * Sn + s] = o;
      }
    }
  } else {  // MODE 1: stage through LDS for coalesced bf16 row-major store
    ushort* Cs = lds;   // 128 x 136
#pragma unroll
    for (int mi = 0; mi < 4; ++mi)
#pragma unroll
      for (int ni = 0; ni < 4; ++ni) {
        int col = wc + ni * 16 + l16;
#pragma unroll
        for (int r = 0; r < 4; ++r)
          Cs[(wr + mi * 16 + quad * 4 + r) * 136 + col] = f2bf(acc[mi][ni][r]);
      }
    __syncthreads();
    ushort* C = (ushort*)Cout;
#pragma unroll
    for (int i = 0; i < 8; ++i) {
      int c = t + i * 256;
      int row = c >> 4, cg = (c & 15) * 8;
      *(ulonglong2*)&C[(size_t)(m0 + row) * N + n0 + cg] =
          *(const ulonglong2*)&Cs[row * 136 + cg];
    }
  }
}

// ---------------------------------------------------------------------------
// Fused flash-style attention: scores + causal softmax + AV in one kernel.
// Per block: (hb, qt) with a 64-row q-tile; two passes over 128-wide k-tiles
// (kt <= diag). Pass 1: online row max/sum. Pass 2: recompute S, write
// normalized P (fp32) to attn via LDS round-trip, MFMA P@V into O.
// Also zero-fills strict-upper k-tiles of attn.
// Layout: 256 threads = 4 waves, wave w owns q-rows [w*16, w*16+16).
// ---------------------------------------------------------------------------
__global__ __launch_bounds__(256, 2) void attn_fused(
    const ushort* __restrict__ Qp, const ushort* __restrict__ Kp,
    const ushort* __restrict__ Vt, float* __restrict__ attn,
    ushort* __restrict__ Cc) {
  const int hb = blockIdx.x, qt = blockIdx.y;
  const int h = hb >> 2, b = hb & 3;
  const int q0 = qt * 64;
  const int nkt = (qt >> 1) + 1;   // 128-wide k-tiles covering k <= q0+63

  __shared__ ushort Qs[64 * 72];    // [q][c] d=64, pad to 72
  __shared__ ushort Ks[128 * 72];   // [k][c]
  __shared__ ushort Vs[64 * 136];   // [j][k] 128-wide k-tile, pad to 136
  __shared__ ushort Ps[64 * 136];   // [q][k] P tile bf16

  const int t = threadIdx.x;
  const int w = t >> 6, lane = t & 63;
  const int l16 = lane & 15, quad = lane >> 4;

  // ---- zero-fill strict-upper attn tiles for these 64 q-rows ----
  for (int ktz = nkt; ktz < 8; ++ktz) {
    const int k0 = ktz * 128;
#pragma unroll
    for (int i = 0; i < 4; ++i) {
      int cc = t + i * 256;
      int row = cc >> 4, cg = (cc & 15) * 8;
      float* dst = &attn[((size_t)hb * Sn + q0 + row) * Sn + k0 + cg];
      *(float4*)&dst[0] = make_float4(0.f, 0.f, 0.f, 0.f);
      *(float4*)&dst[4] = make_float4(0.f, 0.f, 0.f, 0.f);
    }
  }

  // ---- load Q tile (64 x 64 bf16) ----
#pragma unroll
  for (int i = 0; i < 2; ++i) {
    int cc = t + i * 256;
    int row = cc >> 3, cg = (cc & 7) * 8;
    *(ulonglong2*)&Qs[row * 72 + cg] =
        *(const ulonglong2*)&Qp[((size_t)b * Sn + q0 + row) * Dn + h * dHn + cg];
  }

  float m_run[4], l_run[4];
#pragma unroll
  for (int r = 0; r < 4; ++r) { m_run[r] = -3e38f; l_run[r] = 0.f; }

  // ================= PASS 1: row max & sum =================
  for (int kt = 0; kt < nkt; ++kt) {
    const int k0 = kt * 128;
#pragma unroll
    for (int i = 0; i < 4; ++i) {
      int cc = t + i * 256;
      int row = cc >> 3, cg = (cc & 7) * 8;
      *(ulonglong2*)&Ks[row * 72 + cg] =
          *(const ulonglong2*)&Kp[((size_t)b * Sn + k0 + row) * Dn + h * dHn + cg];
    }
    __syncthreads();
    bf16x8 aq[2];
#pragma unroll
    for (int ks = 0; ks < 2; ++ks)
      aq[ks] = *(const bf16x8*)&Qs[(w * 16 + l16) * 72 + ks * 32 + quad * 8];
    f32x4 s[8];
#pragma unroll
    for (int ni = 0; ni < 8; ++ni) {
      f32x4 a = {};
#pragma unroll
      for (int ks = 0; ks < 2; ++ks) {
        bf16x8 bk = *(const bf16x8*)&Ks[(ni * 16 + l16) * 72 + ks * 32 + quad * 8];
        a = __builtin_amdgcn_mfma_f32_16x16x32_bf16(aq[ks], bk, a, 0, 0, 0);
      }
      s[ni] = a;
    }
    float tmax[4] = {-3e38f, -3e38f, -3e38f, -3e38f};
#pragma unroll
    for (int ni = 0; ni < 8; ++ni)
#pragma unroll
      for (int r = 0; r < 4; ++r) {
        int kg = k0 + ni * 16 + l16;
        int qg = q0 + w * 16 + quad * 4 + r;
        float v = (kg <= qg) ? s[ni][r] * 0.125f : -3e38f;
        s[ni][r] = v;
        tmax[r] = fmaxf(tmax[r], v);
      }
#pragma unroll
    for (int d = 1; d < 16; d <<= 1)
#pragma unroll
      for (int r = 0; r < 4; ++r)
        tmax[r] = fmaxf(tmax[r], __shfl_xor(tmax[r], d));
    float mnew[4], tsum[4] = {0.f, 0.f, 0.f, 0.f};
#pragma unroll
    for (int r = 0; r < 4; ++r) mnew[r] = fmaxf(m_run[r], tmax[r]);
#pragma unroll
    for (int ni = 0; ni < 8; ++ni)
#pragma unroll
      for (int r = 0; r < 4; ++r) tsum[r] += __expf(s[ni][r] - mnew[r]);
#pragma unroll
    for (int d = 1; d < 16; d <<= 1)
#pragma unroll
      for (int r = 0; r < 4; ++r) tsum[r] += __shfl_xor(tsum[r], d);
#pragma unroll
    for (int r = 0; r < 4; ++r) {
      l_run[r] = l_run[r] * __expf(m_run[r] - mnew[r]) + tsum[r];
      m_run[r] = mnew[r];
    }
    __syncthreads();
  }
  float inv_l[4];
#pragma unroll
  for (int r = 0; r < 4; ++r) inv_l[r] = 1.0f / l_run[r];

  // ================= PASS 2: P writes + O accumulate =================
  f32x4 acc_o[4] = {};
  for (int kt = 0; kt < nkt; ++kt) {
    const int k0 = kt * 128;
#pragma unroll
    for (int i = 0; i < 4; ++i) {
      int cc = t + i * 256;
      int row = cc >> 3, cg = (cc & 7) * 8;
      *(ulonglong2*)&Ks[row * 72 + cg] =
          *(const ulonglong2*)&Kp[((size_t)b * Sn + k0 + row) * Dn + h * dHn + cg];
    }
#pragma unroll
    for (int i = 0; i < 4; ++i) {
      int cc = t + i * 256;
      int row = cc >> 4, cg = (cc & 15) * 8;
      *(ulonglong2*)&Vs[row * 136 + cg] =
          *(const ulonglong2*)&Vt[((size_t)b * Dn + h * dHn + row) * Sn + k0 + cg];
    }
    __syncthreads();
    bf16x8 aq[2];
#pragma unroll
    for (int ks = 0; ks < 2; ++ks)
      aq[ks] = *(const bf16x8*)&Qs[(w * 16 + l16) * 72 + ks * 32 + quad * 8];
    f32x4 s[8];
#pragma unroll
    for (int ni = 0; ni < 8; ++ni) {
      f32x4 a = {};
#pragma unroll
      for (int ks = 0; ks < 2; ++ks) {
        bf16x8 bk = *(const bf16x8*)&Ks[(ni * 16 + l16) * 72 + ks * 32 + quad * 8];
        a = __builtin_amdgcn_mfma_f32_16x16x32_bf16(aq[ks], bk, a, 0, 0, 0);
      }
      s[ni] = a;
    }
    // P = exp(s - m) / l ; masked entries give exp(-huge) == 0
#pragma unroll
    for (int ni = 0; ni < 8; ++ni)
#pragma unroll
      for (int r = 0; r < 4; ++r) {
        int kg = k0 + ni * 16 + l16;
        int qg = q0 + w * 16 + quad * 4 + r;
        float v = (kg <= qg) ? s[ni][r] * 0.125f : -3e38f;
        float p = __expf(v - m_run[r]) * inv_l[r];
        Ps[(w * 16 + quad * 4 + r) * 136 + ni * 16 + l16] = f2bf(p);
      }
    // O += P @ V^T-form (A = own wave's 16 P rows; B = Vs rows j, k-contig)
#pragma unroll
    for (int ks = 0; ks < 4; ++ks) {
      bf16x8 ap = *(const bf16x8*)&Ps[(w * 16 + l16) * 136 + ks * 32 + quad * 8];
#pragma unroll
      for (int ni = 0; ni < 4; ++ni) {
        bf16x8 bv = *(const bf16x8*)&Vs[(ni * 16 + l16) * 136 + ks * 32 + quad * 8];
        acc_o[ni] = __builtin_amdgcn_mfma_f32_16x16x32_bf16(ap, bv, acc_o[ni], 0, 0, 0);
      }
    }
    __syncthreads();   // all waves' Ps written before cross-wave attn store
    // coalesced fp32 attn store from Ps
#pragma unroll
    for (int i = 0; i < 4; ++i) {
      int cc = t + i * 256;
      int row = cc >> 4, cg = (cc & 15) * 8;
      bf16x8 pv = *(const bf16x8*)&Ps[row * 136 + cg];
      float* dst = &attn[((size_t)hb * Sn + q0 + row) * Sn + k0 + cg];
      *(float4*)&dst[0] = make_float4(bf2f((ushort)pv[0]), bf2f((ushort)pv[1]),
                                      bf2f((ushort)pv[2]), bf2f((ushort)pv[3]));
      *(float4*)&dst[4] = make_float4(bf2f((ushort)pv[4]), bf2f((ushort)pv[5]),
                                      bf2f((ushort)pv[6]), bf2f((ushort)pv[7]));
    }
  }
  // ---- O epilogue -> concat bf16 [B*S, D] ----
#pragma unroll
  for (int ni = 0; ni < 4; ++ni)
#pragma unroll
    for (int r = 0; r < 4; ++r) {
      int q = q0 + w * 16 + quad * 4 + r;
      int j = ni * 16 + l16;
      Cc[((size_t)b * Sn + q) * Dn + h * dHn + j] = f2bf(acc_o[ni][r]);
    }
}

// ---------------------------------------------------------------------------
// In-place row LayerNorm on out[B*S, D].  grid (B*S), 256 threads.
// ---------------------------------------------------------------------------
__global__ __launch_bounds__(256) void ln_kernel(
    float* __restrict__ out, const float* __restrict__ gamma,
    const float* __restrict__ beta) {
  const int row = blockIdx.x;
  float* p = out + (size_t)row * Dn;
  const int t = threadIdx.x;
  float v[4];
  float s = 0.f, s2 = 0.f;
#pragma unroll
  for (int i = 0; i < 4; ++i) {
    v[i] = p[t + i * 256];
    s += v[i];
    s2 += v[i] * v[i];
  }
  __shared__ float r1[256], r2[256];
  r1[t] = s; r2[t] = s2;
  __syncthreads();
  for (int st = 128; st > 0; st >>= 1) {
    if (t < st) { r1[t] += r1[t + st]; r2[t] += r2[t + st]; }
    __syncthreads();
  }
  const float mu  = r1[0] * (1.0f / Dn);
  const float var = r2[0] * (1.0f / Dn) - mu * mu;
  const float rstd = rsqrtf(var + 1e-5f);
#pragma unroll
  for (int i = 0; i < 4; ++i) {
    int c = t + i * 256;
    p[c] = (v[i] - mu) * rstd * gamma[c] + beta[c];
  }
}

// ---------------------------------------------------------------------------
extern "C" void kernel_launch(void* const* d_in, const int* in_sizes, int n_in,
                              void* d_out, int out_size, void* d_ws, size_t ws_size,
                              hipStream_t stream) {
  const float* q_in  = (const float*)d_in[0];
  const float* k_in  = (const float*)d_in[1];
  const float* v_in  = (const float*)d_in[2];
  const float* Wq    = (const float*)d_in[3];
  const float* Wk    = (const float*)d_in[4];
  const float* Wv    = (const float*)d_in[5];
  const float* Wo    = (const float*)d_in[6];
  const float* gamma = (const float*)d_in[7];
  const float* beta  = (const float*)d_in[8];

  float* out  = (float*)d_out;                // [B,S,D]
  float* attn = out + (size_t)Bn * Sn * Dn;   // [H,B,S,S]

  const size_t QN = (size_t)Bn * Sn * Dn;     // 4M elements
  ushort* ws  = (ushort*)d_ws;
  ushort* qbf = ws;                           // [B*S, D] bf16
  ushort* kbf = qbf + QN;
  ushort* vbf = kbf + QN;
  ushort* WqT = vbf + QN;                     // [N,K] bf16, 1M each
  ushort* WkT = WqT + (size_t)Dn * Dn;
  ushort* WvT = WkT + (size_t)Dn * Dn;
  ushort* WoT = WvT + (size_t)Dn * Dn;
  ushort* Qp  = WoT + (size_t)Dn * Dn;        // [B*S, D] bf16
  ushort* Kp  = Qp + QN;
  ushort* Vt  = Kp + QN;                      // [B][D][S] bf16
  ushort* Cc  = Vt + QN;                      // [B*S, D] bf16

  cast_kernel<<<QN / 1024, 256, 0, stream>>>(q_in, qbf);
  cast_kernel<<<QN / 1024, 256, 0, stream>>>(k_in, kbf);
  cast_kernel<<<QN / 1024, 256, 0, stream>>>(v_in, vbf);

  dim3 tg(Dn / 64, Dn / 64);
  transpose_cast_kernel<<<tg, 256, 0, stream>>>(Wq, WqT, Dn, Dn);
  transpose_cast_kernel<<<tg, 256, 0, stream>>>(Wk, WkT, Dn, Dn);
  transpose_cast_kernel<<<tg, 256, 0, stream>>>(Wv, WvT, Dn, Dn);
  transpose_cast_kernel<<<tg, 256, 0, stream>>>(Wo, WoT, Dn, Dn);

  dim3 gg(Dn / 128, MROWS / 128);             // (8, 32)
  gemm_bt<1><<<gg, 256, 0, stream>>>(qbf, WqT, nullptr, Qp, MROWS, Dn, Dn);
  gemm_bt<1><<<gg, 256, 0, stream>>>(kbf, WkT, nullptr, Kp, MROWS, Dn, Dn);
  gemm_bt<2><<<gg, 256, 0, stream>>>(vbf, WvT, nullptr, Vt, MROWS, Dn, Dn);

  attn_fused<<<dim3(HB, Sn / 64), 256, 0, stream>>>(Qp, Kp, Vt, attn, Cc);

  gemm_bt<0><<<gg, 256, 0, stream>>>(Cc, WoT, q_in, out, MROWS, Dn, Dn);
  ln_kernel<<<MROWS, 256, 0, stream>>>(out, gamma, beta);
}